// Round 1
// baseline (3538.662 us; speedup 1.0000x reference)
//
#include <hip/hip_runtime.h>
#include <cstdint>
#include <cstddef>

// ---------------- problem constants (from setup_inputs) ----------------
constexpr int Nn   = 50000;            // nodes
constexpr int Ee   = 800000;           // edges (without self loops)
constexpr int ETot = Ee + Nn;          // 850000 with self loops
constexpr int Fin  = 256;              // input features
constexpr int H1   = 8;                // heads layer 1
constexpr int C1h  = 32;               // channels/head layer 1
constexpr int HC1  = 256;              // H1*C1h
constexpr int C2   = 40;               // classes (layer 2, 1 head)
constexpr float SLOPE = 0.2f;          // leaky_relu negative slope

__device__ __forceinline__ void atomAddF(float* p, float v) {
    __hip_atomic_fetch_add(p, v, __ATOMIC_RELAXED, __HIP_MEMORY_SCOPE_AGENT);
}

// ---------------- init: out[n][c] = bias[c] ----------------
__global__ void k_rowbias(float* __restrict__ o, const float* __restrict__ b,
                          int n, int cols) {
    int t = blockIdx.x * blockDim.x + threadIdx.x;
    if (t < n * cols) o[t] = b[t % cols];
}

// ---------------- GEMM1: [M,256] x [256,256] -> [M,256] ----------------
__global__ __launch_bounds__(256) void k_gemm1(const float* __restrict__ A,
                                               const float* __restrict__ B,
                                               float* __restrict__ C, int M) {
    constexpr int BM = 64, BN = 64, BK = 16, K = 256, NC = 256;
    __shared__ float As[BK][BM];   // k-major (transposed on store)
    __shared__ float Bs[BK][BN];
    const int tid = threadIdx.x;
    const int bm = blockIdx.x * BM, bn = blockIdx.y * BN;
    const int tm = (tid >> 4) << 2, tn = (tid & 15) << 2;
    const int lr = tid >> 2, lk = (tid & 3) << 2;      // A loader: row, k-off
    const int br = tid >> 4, bc = (tid & 15) << 2;     // B loader: k-row, col-off
    float acc[4][4] = {};
    for (int k0 = 0; k0 < K; k0 += BK) {
        float4 av = make_float4(0.f, 0.f, 0.f, 0.f);
        int gr = bm + lr;
        if (gr < M) av = *(const float4*)(A + (size_t)gr * K + k0 + lk);
        As[lk + 0][lr] = av.x; As[lk + 1][lr] = av.y;
        As[lk + 2][lr] = av.z; As[lk + 3][lr] = av.w;
        *(float4*)&Bs[br][bc] = *(const float4*)(B + (size_t)(k0 + br) * NC + bn + bc);
        __syncthreads();
#pragma unroll
        for (int kk = 0; kk < BK; kk++) {
            float4 a4 = *(const float4*)&As[kk][tm];
            float4 b4 = *(const float4*)&Bs[kk][tn];
            float a[4] = {a4.x, a4.y, a4.z, a4.w};
            float b[4] = {b4.x, b4.y, b4.z, b4.w};
#pragma unroll
            for (int i = 0; i < 4; i++)
#pragma unroll
                for (int j = 0; j < 4; j++) acc[i][j] += a[i] * b[j];
        }
        __syncthreads();
    }
#pragma unroll
    for (int i = 0; i < 4; i++) {
        int r = bm + tm + i;
        if (r < M)
            *(float4*)(C + (size_t)r * NC + bn + tn) =
                make_float4(acc[i][0], acc[i][1], acc[i][2], acc[i][3]);
    }
}

// ---------------- GEMM2: [M,256] x [256,40] -> [M,40] ----------------
__global__ __launch_bounds__(256) void k_gemm2(const float* __restrict__ A,
                                               const float* __restrict__ B,
                                               float* __restrict__ C, int M) {
    constexpr int K = 256, NC = 40, BM = 32, BK = 32;
    __shared__ float Ws[K * NC];       // full W2: 40 KB
    __shared__ float As[BM][BK];
    const int tid = threadIdx.x;
    for (int i = tid; i < K * NC; i += 256) Ws[i] = B[i];
    const int bm = blockIdx.x * BM;
    const int r = tid >> 3, g = tid & 7;   // row 0..31, col-group 0..7 (5 cols each)
    float acc[5] = {};
    for (int k0 = 0; k0 < K; k0 += BK) {
        int ko = (tid & 7) << 2;
        float4 v = make_float4(0.f, 0.f, 0.f, 0.f);
        if (bm + r < M) v = *(const float4*)(A + (size_t)(bm + r) * K + k0 + ko);
        *(float4*)&As[r][ko] = v;
        __syncthreads();
#pragma unroll
        for (int kk = 0; kk < BK; kk++) {
            float a = As[r][kk];
#pragma unroll
            for (int j = 0; j < 5; j++) acc[j] += a * Ws[(k0 + kk) * NC + g * 5 + j];
        }
        __syncthreads();
    }
    if (bm + r < M) {
#pragma unroll
        for (int j = 0; j < 5; j++) C[(size_t)(bm + r) * NC + g * 5 + j] = acc[j];
    }
}

// ---------------- per-node attention coefficients ----------------
template <int H, int C>
__global__ void k_alpha(const float* __restrict__ h, const float* __restrict__ a_s,
                        const float* __restrict__ a_d, float* __restrict__ asrc,
                        float* __restrict__ adst, int N) {
    __shared__ float ls[H * C], ldd[H * C];
    for (int i = threadIdx.x; i < H * C; i += blockDim.x) { ls[i] = a_s[i]; ldd[i] = a_d[i]; }
    __syncthreads();
    int t = blockIdx.x * blockDim.x + threadIdx.x;
    if (t >= N * H) return;
    int n = t / H, hh = t % H;
    const float* row = h + (size_t)n * (H * C) + hh * C;
    float s = 0.f, dd = 0.f;
#pragma unroll
    for (int c = 0; c < C; c += 4) {
        float4 v = *(const float4*)(row + c);
        s  += v.x * ls[hh * C + c] + v.y * ls[hh * C + c + 1] +
              v.z * ls[hh * C + c + 2] + v.w * ls[hh * C + c + 3];
        dd += v.x * ldd[hh * C + c] + v.y * ldd[hh * C + c + 1] +
              v.z * ldd[hh * C + c + 2] + v.w * ldd[hh * C + c + 3];
    }
    asrc[t] = s;
    adst[t] = dd;
}

// ---------------- edge pass 1: p = exp(leaky(as[src]+ad[dst])), denom += p ----
// (no segment-max: logits are O(1), exp is safe; alpha = p/denom is invariant)
template <int H>
__global__ void k_edge_logits(const int* __restrict__ srcA, const int* __restrict__ dstA,
                              const float* __restrict__ asrc, const float* __restrict__ adst,
                              float* __restrict__ p, float* __restrict__ denom) {
    int e = blockIdx.x * blockDim.x + threadIdx.x;
    if (e >= ETot) return;
    int s, d;
    if (e < Ee) { s = srcA[e]; d = dstA[e]; } else { s = e - Ee; d = s; }
#pragma unroll
    for (int h = 0; h < H; h++) {
        float l = asrc[s * H + h] + adst[d * H + h];
        l = l > 0.f ? l : SLOPE * l;
        float pe = __expf(l);
        p[(size_t)e * H + h] = pe;
        atomAddF(&denom[(size_t)d * H + h], pe);
    }
}

// ---------------- edge pass 2 layer 1: wave per edge, 4 ch/lane ----------------
__global__ __launch_bounds__(256) void k_aggr1(const int* __restrict__ srcA,
                                               const int* __restrict__ dstA,
                                               const float* __restrict__ p,
                                               const float* __restrict__ denom,
                                               const float* __restrict__ h1,
                                               float* __restrict__ out) {
    int gid = blockIdx.x * 256 + threadIdx.x;
    int e = gid >> 6;
    int lane = threadIdx.x & 63;
    if (e >= ETot) return;
    int s, d;
    if (e < Ee) { s = srcA[e]; d = dstA[e]; } else { s = e - Ee; d = s; }
    int h = lane >> 3;                       // 8 lanes per head
    float coeff = p[(size_t)e * 8 + h] / denom[(size_t)d * 8 + h];
    float4 v = *(const float4*)(h1 + (size_t)s * 256 + (lane << 2));
    float* o = out + (size_t)d * 256 + (lane << 2);
    atomAddF(o + 0, coeff * v.x);
    atomAddF(o + 1, coeff * v.y);
    atomAddF(o + 2, coeff * v.z);
    atomAddF(o + 3, coeff * v.w);
}

// ---------------- ELU in place ----------------
__global__ void k_elu(float* __restrict__ x, int n) {
    int t = blockIdx.x * blockDim.x + threadIdx.x;
    if (t < n) { float v = x[t]; x[t] = v > 0.f ? v : __expf(v) - 1.f; }
}

// ---------------- edge pass 2 layer 2: thread per (edge, channel) -------------
__global__ void k_aggr2(const int* __restrict__ srcA, const int* __restrict__ dstA,
                        const float* __restrict__ p, const float* __restrict__ denom,
                        const float* __restrict__ h2, float* __restrict__ out) {
    int t = blockIdx.x * blockDim.x + threadIdx.x;
    if (t >= ETot * C2) return;
    int e = t / C2, c = t - e * C2;
    int s, d;
    if (e < Ee) { s = srcA[e]; d = dstA[e]; } else { s = e - Ee; d = s; }
    float coeff = p[e] / denom[d];
    atomAddF(out + (size_t)d * C2 + c, coeff * h2[(size_t)s * C2 + c]);
}

// ---------------- launch ----------------
extern "C" void kernel_launch(void* const* d_in, const int* in_sizes, int n_in,
                              void* d_out, int out_size, void* d_ws, size_t ws_size,
                              hipStream_t stream) {
    const float* x   = (const float*)d_in[0];
    const int*   ei  = (const int*)d_in[1];
    const float* w1  = (const float*)d_in[2];
    const float* as1 = (const float*)d_in[3];
    const float* ad1 = (const float*)d_in[4];
    const float* b1  = (const float*)d_in[5];
    const float* w2  = (const float*)d_in[6];
    const float* as2 = (const float*)d_in[7];
    const float* ad2 = (const float*)d_in[8];
    const float* b2  = (const float*)d_in[9];
    float* outp = (float*)d_out;

    const int* srcA = ei;          // edge_index[0]
    const int* dstA = ei + Ee;     // edge_index[1]

    float* W = (float*)d_ws;
    size_t o = 0;
    float* h1     = W + o; o += (size_t)Nn * HC1;      // 12.8M
    float* asrc1  = W + o; o += (size_t)Nn * H1;
    float* adst1  = W + o; o += (size_t)Nn * H1;
    float* denom1 = W + o; o += (size_t)Nn * H1;
    float* p1     = W + o; o += (size_t)ETot * H1;     // 6.8M
    float* out1   = W + o; o += (size_t)Nn * HC1;      // 12.8M (h after agg+elu)
    float* h2     = W + o; o += (size_t)Nn * C2;       // 2M
    size_t npad = ((Nn + 63) / 64) * 64;
    float* asrc2  = W + o; o += npad;
    float* adst2  = W + o; o += npad;
    float* denom2 = W + o; o += npad;
    float* p2     = W + o; o += (size_t)ETot;

    // per-call init (harness does not re-poison between replays)
    hipMemsetAsync(denom1, 0, (size_t)Nn * H1 * sizeof(float), stream);
    hipMemsetAsync(denom2, 0, npad * sizeof(float), stream);
    k_rowbias<<<(Nn * HC1 + 255) / 256, 256, 0, stream>>>(out1, b1, Nn, HC1);
    k_rowbias<<<(Nn * C2 + 255) / 256, 256, 0, stream>>>(outp, b2, Nn, C2);

    // ---- layer 1 ----
    dim3 g1((Nn + 63) / 64, 4);
    k_gemm1<<<g1, 256, 0, stream>>>(x, w1, h1, Nn);
    k_alpha<H1, C1h><<<(Nn * H1 + 255) / 256, 256, 0, stream>>>(h1, as1, ad1, asrc1, adst1, Nn);
    k_edge_logits<H1><<<(ETot + 255) / 256, 256, 0, stream>>>(srcA, dstA, asrc1, adst1, p1, denom1);
    k_aggr1<<<(int)(((size_t)ETot * 64 + 255) / 256), 256, 0, stream>>>(srcA, dstA, p1, denom1, h1, out1);
    k_elu<<<(Nn * HC1 + 255) / 256, 256, 0, stream>>>(out1, Nn * HC1);

    // ---- layer 2 ----
    k_gemm2<<<(Nn + 31) / 32, 256, 0, stream>>>(out1, w2, h2, Nn);
    k_alpha<1, C2><<<(Nn + 255) / 256, 256, 0, stream>>>(h2, as2, ad2, asrc2, adst2, Nn);
    k_edge_logits<1><<<(ETot + 255) / 256, 256, 0, stream>>>(srcA, dstA, asrc2, adst2, p2, denom2);
    k_aggr2<<<(int)(((size_t)ETot * C2 + 255) / 256), 256, 0, stream>>>(srcA, dstA, p2, denom2, h2, outp);
}

// Round 2
// 495.550 us; speedup vs baseline: 7.1409x; 7.1409x over previous
//
#include <hip/hip_runtime.h>
#include <cstdint>
#include <cstddef>

// ---------------- problem constants (from setup_inputs) ----------------
constexpr int Nn   = 50000;            // nodes
constexpr int Ee   = 800000;           // edges (without self loops)
constexpr int ETot = Ee + Nn;          // 850000 with self loops
constexpr int H1   = 8;                // heads layer 1
constexpr int C1h  = 32;               // channels/head layer 1
constexpr int HC1  = 256;              // H1*C1h
constexpr int C2   = 40;               // classes (layer 2, 1 head)
constexpr float SLOPE = 0.2f;          // leaky_relu negative slope
constexpr int NB_SCAN = (Nn + 255) / 256;   // 196 scan blocks

// ================= CSR build (histogram -> scan -> scatter) =================
__global__ void k_hist(const int* __restrict__ dstA, int* __restrict__ counts) {
    int e = blockIdx.x * blockDim.x + threadIdx.x;
    if (e >= ETot) return;
    int d = (e < Ee) ? dstA[e] : e - Ee;
    atomicAdd(&counts[d], 1);
}

__global__ __launch_bounds__(256) void k_scan_block(const int* __restrict__ counts,
                                                    int* __restrict__ exsc,
                                                    int* __restrict__ bsum) {
    __shared__ int sm[256];
    int i = blockIdx.x * 256 + threadIdx.x;
    int v = (i < Nn) ? counts[i] : 0;
    sm[threadIdx.x] = v;
    __syncthreads();
#pragma unroll
    for (int off = 1; off < 256; off <<= 1) {
        int t = (threadIdx.x >= off) ? sm[threadIdx.x - off] : 0;
        __syncthreads();
        sm[threadIdx.x] += t;
        __syncthreads();
    }
    if (i < Nn) exsc[i] = sm[threadIdx.x] - v;
    if (threadIdx.x == 255) bsum[blockIdx.x] = sm[255];
}

__global__ __launch_bounds__(256) void k_scan_top(const int* __restrict__ bsum,
                                                  int* __restrict__ boff) {
    __shared__ int sm[256];
    int t = threadIdx.x;
    int v = (t < NB_SCAN) ? bsum[t] : 0;
    sm[t] = v;
    __syncthreads();
#pragma unroll
    for (int off = 1; off < 256; off <<= 1) {
        int x = (t >= off) ? sm[t - off] : 0;
        __syncthreads();
        sm[t] += x;
        __syncthreads();
    }
    if (t < NB_SCAN) boff[t] = sm[t] - v;
}

__global__ void k_finalize_off(const int* __restrict__ exsc, const int* __restrict__ boff,
                               int* __restrict__ row_off, int* __restrict__ cursor) {
    int i = blockIdx.x * blockDim.x + threadIdx.x;
    if (i < Nn) {
        int r = exsc[i] + boff[i >> 8];
        row_off[i] = r;
        cursor[i] = r;
    }
    if (i == 0) row_off[Nn] = ETot;
}

__global__ void k_scatter(const int* __restrict__ srcA, const int* __restrict__ dstA,
                          int* __restrict__ cursor, int* __restrict__ csr_src) {
    int e = blockIdx.x * blockDim.x + threadIdx.x;
    if (e >= ETot) return;
    int s, d;
    if (e < Ee) { s = srcA[e]; d = dstA[e]; } else { s = e - Ee; d = s; }
    int pos = atomicAdd(&cursor[d], 1);
    csr_src[pos] = s;
}

// ---------------- GEMM1: [M,256] x [256,256] -> [M,256] ----------------
__global__ __launch_bounds__(256) void k_gemm1(const float* __restrict__ A,
                                               const float* __restrict__ B,
                                               float* __restrict__ C, int M) {
    constexpr int BM = 64, BN = 64, BK = 16, K = 256, NC = 256;
    __shared__ float As[BK][BM];   // k-major (transposed on store)
    __shared__ float Bs[BK][BN];
    const int tid = threadIdx.x;
    const int bm = blockIdx.x * BM, bn = blockIdx.y * BN;
    const int tm = (tid >> 4) << 2, tn = (tid & 15) << 2;
    const int lr = tid >> 2, lk = (tid & 3) << 2;      // A loader: row, k-off
    const int br = tid >> 4, bc = (tid & 15) << 2;     // B loader: k-row, col-off
    float acc[4][4] = {};
    for (int k0 = 0; k0 < K; k0 += BK) {
        float4 av = make_float4(0.f, 0.f, 0.f, 0.f);
        int gr = bm + lr;
        if (gr < M) av = *(const float4*)(A + (size_t)gr * K + k0 + lk);
        As[lk + 0][lr] = av.x; As[lk + 1][lr] = av.y;
        As[lk + 2][lr] = av.z; As[lk + 3][lr] = av.w;
        *(float4*)&Bs[br][bc] = *(const float4*)(B + (size_t)(k0 + br) * NC + bn + bc);
        __syncthreads();
#pragma unroll
        for (int kk = 0; kk < BK; kk++) {
            float4 a4 = *(const float4*)&As[kk][tm];
            float4 b4 = *(const float4*)&Bs[kk][tn];
            float a[4] = {a4.x, a4.y, a4.z, a4.w};
            float b[4] = {b4.x, b4.y, b4.z, b4.w};
#pragma unroll
            for (int i = 0; i < 4; i++)
#pragma unroll
                for (int j = 0; j < 4; j++) acc[i][j] += a[i] * b[j];
        }
        __syncthreads();
    }
#pragma unroll
    for (int i = 0; i < 4; i++) {
        int r = bm + tm + i;
        if (r < M)
            *(float4*)(C + (size_t)r * NC + bn + tn) =
                make_float4(acc[i][0], acc[i][1], acc[i][2], acc[i][3]);
    }
}

// ---------------- GEMM2: [M,256] x [256,40] -> [M,40] ----------------
__global__ __launch_bounds__(256) void k_gemm2(const float* __restrict__ A,
                                               const float* __restrict__ B,
                                               float* __restrict__ C, int M) {
    constexpr int K = 256, NC = 40, BM = 32, BK = 32;
    __shared__ float Ws[K * NC];       // full W2: 40 KB
    __shared__ float As[BM][BK];
    const int tid = threadIdx.x;
    for (int i = tid; i < K * NC; i += 256) Ws[i] = B[i];
    const int bm = blockIdx.x * BM;
    const int r = tid >> 3, g = tid & 7;   // row 0..31, col-group 0..7 (5 cols each)
    float acc[5] = {};
    for (int k0 = 0; k0 < K; k0 += BK) {
        int ko = (tid & 7) << 2;
        float4 v = make_float4(0.f, 0.f, 0.f, 0.f);
        if (bm + r < M) v = *(const float4*)(A + (size_t)(bm + r) * K + k0 + ko);
        *(float4*)&As[r][ko] = v;
        __syncthreads();
#pragma unroll
        for (int kk = 0; kk < BK; kk++) {
            float a = As[r][kk];
#pragma unroll
            for (int j = 0; j < 5; j++) acc[j] += a * Ws[(k0 + kk) * NC + g * 5 + j];
        }
        __syncthreads();
    }
    if (bm + r < M) {
#pragma unroll
        for (int j = 0; j < 5; j++) C[(size_t)(bm + r) * NC + g * 5 + j] = acc[j];
    }
}

// ---------------- per-node attention coefficients ----------------
template <int H, int C>
__global__ void k_alpha(const float* __restrict__ h, const float* __restrict__ a_s,
                        const float* __restrict__ a_d, float* __restrict__ asrc,
                        float* __restrict__ adst, int N) {
    __shared__ float ls[H * C], ldd[H * C];
    for (int i = threadIdx.x; i < H * C; i += blockDim.x) { ls[i] = a_s[i]; ldd[i] = a_d[i]; }
    __syncthreads();
    int t = blockIdx.x * blockDim.x + threadIdx.x;
    if (t >= N * H) return;
    int n = t / H, hh = t % H;
    const float* row = h + (size_t)n * (H * C) + hh * C;
    float s = 0.f, dd = 0.f;
#pragma unroll
    for (int c = 0; c < C; c += 4) {
        float4 v = *(const float4*)(row + c);
        s  += v.x * ls[hh * C + c] + v.y * ls[hh * C + c + 1] +
              v.z * ls[hh * C + c + 2] + v.w * ls[hh * C + c + 3];
        dd += v.x * ldd[hh * C + c] + v.y * ldd[hh * C + c + 1] +
              v.z * ldd[hh * C + c + 2] + v.w * ldd[hh * C + c + 3];
    }
    asrc[t] = s;
    adst[t] = dd;
}

// ======== layer-1 aggregation: wave per node, CSR gather, no atomics ========
// lane = (head = lane>>3, 4 channels); fuses edge-softmax + aggregation + bias + ELU.
__global__ __launch_bounds__(256) void k_gat_aggr1(const int* __restrict__ row_off,
                                                   const int* __restrict__ csr_src,
                                                   const float* __restrict__ asrc,
                                                   const float* __restrict__ adst,
                                                   const float* __restrict__ h1,
                                                   const float* __restrict__ bias,
                                                   float* __restrict__ out) {
    int wid = (blockIdx.x * 256 + threadIdx.x) >> 6;   // node id
    if (wid >= Nn) return;
    int lane = threadIdx.x & 63;
    int head = lane >> 3;
    int choff = (lane & 7) << 2;                       // 4 channels within head
    int beg = row_off[wid], end = row_off[wid + 1];
    float ad = adst[(size_t)wid * H1 + head];
    float4 acc = make_float4(0.f, 0.f, 0.f, 0.f);
    float sump = 0.f;
    for (int i = beg; i < end; i++) {
        int s = csr_src[i];
        float l = asrc[(size_t)s * H1 + head] + ad;
        l = l > 0.f ? l : SLOPE * l;
        float pe = __expf(l);
        sump += pe;
        float4 v = *(const float4*)(h1 + (size_t)s * HC1 + head * C1h + choff);
        acc.x += pe * v.x; acc.y += pe * v.y; acc.z += pe * v.z; acc.w += pe * v.w;
    }
    float inv = 1.f / sump;                            // degree >= 1 (self-loop)
    int c0 = head * C1h + choff;
    float4 b4 = *(const float4*)(bias + c0);
    float4 r;
    r.x = acc.x * inv + b4.x; r.y = acc.y * inv + b4.y;
    r.z = acc.z * inv + b4.z; r.w = acc.w * inv + b4.w;
    // fused ELU
    r.x = r.x > 0.f ? r.x : __expf(r.x) - 1.f;
    r.y = r.y > 0.f ? r.y : __expf(r.y) - 1.f;
    r.z = r.z > 0.f ? r.z : __expf(r.z) - 1.f;
    r.w = r.w > 0.f ? r.w : __expf(r.w) - 1.f;
    *(float4*)(out + (size_t)wid * HC1 + c0) = r;
}

// ======== layer-2 aggregation: wave per node, lanes 0..39 = channels ========
__global__ __launch_bounds__(256) void k_gat_aggr2(const int* __restrict__ row_off,
                                                   const int* __restrict__ csr_src,
                                                   const float* __restrict__ asrc,
                                                   const float* __restrict__ adst,
                                                   const float* __restrict__ h2,
                                                   const float* __restrict__ bias,
                                                   float* __restrict__ out) {
    int wid = (blockIdx.x * 256 + threadIdx.x) >> 6;
    if (wid >= Nn) return;
    int lane = threadIdx.x & 63;
    int beg = row_off[wid], end = row_off[wid + 1];
    float ad = adst[wid];
    float acc = 0.f, sump = 0.f;
    for (int i = beg; i < end; i++) {
        int s = csr_src[i];
        float l = asrc[s] + ad;
        l = l > 0.f ? l : SLOPE * l;
        float pe = __expf(l);
        sump += pe;
        if (lane < C2) acc += pe * h2[(size_t)s * C2 + lane];
    }
    if (lane < C2) out[(size_t)wid * C2 + lane] = acc / sump + bias[lane];
}

// ---------------- launch ----------------
extern "C" void kernel_launch(void* const* d_in, const int* in_sizes, int n_in,
                              void* d_out, int out_size, void* d_ws, size_t ws_size,
                              hipStream_t stream) {
    const float* x   = (const float*)d_in[0];
    const int*   ei  = (const int*)d_in[1];
    const float* w1  = (const float*)d_in[2];
    const float* as1 = (const float*)d_in[3];
    const float* ad1 = (const float*)d_in[4];
    const float* b1  = (const float*)d_in[5];
    const float* w2  = (const float*)d_in[6];
    const float* as2 = (const float*)d_in[7];
    const float* ad2 = (const float*)d_in[8];
    const float* b2  = (const float*)d_in[9];
    float* outp = (float*)d_out;

    const int* srcA = ei;          // edge_index[0]
    const int* dstA = ei + Ee;     // edge_index[1]

    char* W = (char*)d_ws;
    size_t o = 0;
    auto allocF = [&](size_t n) { float* p = (float*)(W + o); o += n * 4; return p; };
    auto allocI = [&](size_t n) { int*   p = (int*)(W + o);   o += n * 4; return p; };

    float* h1    = allocF((size_t)Nn * HC1);    // 51.2 MB
    float* out1  = allocF((size_t)Nn * HC1);    // 51.2 MB
    float* h2    = allocF((size_t)Nn * C2);
    float* asrc1 = allocF((size_t)Nn * H1);
    float* adst1 = allocF((size_t)Nn * H1);
    float* asrc2 = allocF(Nn);
    float* adst2 = allocF(Nn);
    int* counts  = allocI(Nn);
    int* exsc    = allocI(Nn);
    int* bsum    = allocI(256);
    int* boff    = allocI(256);
    int* row_off = allocI(Nn + 1);
    int* cursor  = allocI(Nn);
    int* csr_src = allocI(ETot);

    // ---- CSR build (graph is shared by both layers) ----
    hipMemsetAsync(counts, 0, (size_t)Nn * sizeof(int), stream);
    k_hist<<<(ETot + 255) / 256, 256, 0, stream>>>(dstA, counts);
    k_scan_block<<<NB_SCAN, 256, 0, stream>>>(counts, exsc, bsum);
    k_scan_top<<<1, 256, 0, stream>>>(bsum, boff);
    k_finalize_off<<<(Nn + 255) / 256, 256, 0, stream>>>(exsc, boff, row_off, cursor);
    k_scatter<<<(ETot + 255) / 256, 256, 0, stream>>>(srcA, dstA, cursor, csr_src);

    // ---- layer 1 ----
    dim3 g1((Nn + 63) / 64, 4);
    k_gemm1<<<g1, 256, 0, stream>>>(x, w1, h1, Nn);
    k_alpha<H1, C1h><<<(Nn * H1 + 255) / 256, 256, 0, stream>>>(h1, as1, ad1, asrc1, adst1, Nn);
    k_gat_aggr1<<<(int)(((size_t)Nn * 64 + 255) / 256), 256, 0, stream>>>(
        row_off, csr_src, asrc1, adst1, h1, b1, out1);

    // ---- layer 2 ----
    k_gemm2<<<(Nn + 31) / 32, 256, 0, stream>>>(out1, w2, h2, Nn);
    k_alpha<1, C2><<<(Nn + 255) / 256, 256, 0, stream>>>(h2, as2, ad2, asrc2, adst2, Nn);
    k_gat_aggr2<<<(int)(((size_t)Nn * 64 + 255) / 256), 256, 0, stream>>>(
        row_off, csr_src, asrc2, adst2, h2, b2, outp);
}

// Round 3
// 478.928 us; speedup vs baseline: 7.3887x; 1.0347x over previous
//
#include <hip/hip_runtime.h>
#include <cstdint>
#include <cstddef>

// ---------------- problem constants (from setup_inputs) ----------------
constexpr int Nn   = 50000;            // nodes
constexpr int Ee   = 800000;           // edges (without self loops)
constexpr int ETot = Ee + Nn;          // 850000 with self loops
constexpr int H1   = 8;                // heads layer 1
constexpr int C1h  = 32;               // channels/head layer 1
constexpr int HC1  = 256;              // H1*C1h
constexpr int C2   = 40;               // classes (layer 2, 1 head)
constexpr float SLOPE = 0.2f;          // leaky_relu negative slope
constexpr int NB_SCAN = (Nn + 255) / 256;   // 196 scan blocks

typedef __attribute__((ext_vector_type(8))) short bf16x8;   // 8 bf16 (4 VGPRs)
typedef __attribute__((ext_vector_type(4))) float f32x4;    // MFMA accumulator

__device__ __forceinline__ ushort f2bf(float f) {           // RNE f32->bf16
    uint u = __float_as_uint(f);
    u += 0x7fffu + ((u >> 16) & 1u);
    return (ushort)(u >> 16);
}
__device__ __forceinline__ float bf2f(ushort b) {
    return __uint_as_float(((uint)b) << 16);
}

// ================= split x into bf16 hi/lo =================
__global__ void k_split(const float* __restrict__ x, ushort* __restrict__ hi,
                        ushort* __restrict__ lo, int n4) {
    int t = blockIdx.x * blockDim.x + threadIdx.x;
    if (t >= n4) return;
    float4 v = *(const float4*)(x + (size_t)t * 4);
    ushort4 h, l;
    h.x = f2bf(v.x); l.x = f2bf(v.x - bf2f(h.x));
    h.y = f2bf(v.y); l.y = f2bf(v.y - bf2f(h.y));
    h.z = f2bf(v.z); l.z = f2bf(v.z - bf2f(h.z));
    h.w = f2bf(v.w); l.w = f2bf(v.w - bf2f(h.w));
    *(ushort4*)(hi + (size_t)t * 4) = h;
    *(ushort4*)(lo + (size_t)t * 4) = l;
}

// ======= W1 [256][256] -> WT' [256 cols][768 k'] bf16: [Whi; Whi; Wlo] =======
__global__ void k_wsplit(const float* __restrict__ W, ushort* __restrict__ WT) {
    int idx = blockIdx.x * blockDim.x + threadIdx.x;   // 65536
    if (idx >= 256 * 256) return;
    int k = idx & 255, col = idx >> 8;
    float w = W[(size_t)k * 256 + col];
    ushort h = f2bf(w), l = f2bf(w - bf2f(h));
    WT[(size_t)col * 768 + k]       = h;
    WT[(size_t)col * 768 + 256 + k] = h;
    WT[(size_t)col * 768 + 512 + k] = l;
}

// ================= CSR build (histogram -> scan -> scatter) =================
__global__ void k_hist(const int* __restrict__ dstA, int* __restrict__ counts) {
    int e = blockIdx.x * blockDim.x + threadIdx.x;
    if (e >= ETot) return;
    int d = (e < Ee) ? dstA[e] : e - Ee;
    atomicAdd(&counts[d], 1);
}

__global__ __launch_bounds__(256) void k_scan_block(const int* __restrict__ counts,
                                                    int* __restrict__ exsc,
                                                    int* __restrict__ bsum) {
    __shared__ int sm[256];
    int i = blockIdx.x * 256 + threadIdx.x;
    int v = (i < Nn) ? counts[i] : 0;
    sm[threadIdx.x] = v;
    __syncthreads();
#pragma unroll
    for (int off = 1; off < 256; off <<= 1) {
        int t = (threadIdx.x >= off) ? sm[threadIdx.x - off] : 0;
        __syncthreads();
        sm[threadIdx.x] += t;
        __syncthreads();
    }
    if (i < Nn) exsc[i] = sm[threadIdx.x] - v;
    if (threadIdx.x == 255) bsum[blockIdx.x] = sm[255];
}

__global__ __launch_bounds__(256) void k_scan_top(const int* __restrict__ bsum,
                                                  int* __restrict__ boff) {
    __shared__ int sm[256];
    int t = threadIdx.x;
    int v = (t < NB_SCAN) ? bsum[t] : 0;
    sm[t] = v;
    __syncthreads();
#pragma unroll
    for (int off = 1; off < 256; off <<= 1) {
        int x = (t >= off) ? sm[t - off] : 0;
        __syncthreads();
        sm[t] += x;
        __syncthreads();
    }
    if (t < NB_SCAN) boff[t] = sm[t] - v;
}

__global__ void k_finalize_off(const int* __restrict__ exsc, const int* __restrict__ boff,
                               int* __restrict__ row_off, int* __restrict__ cursor) {
    int i = blockIdx.x * blockDim.x + threadIdx.x;
    if (i < Nn) {
        int r = exsc[i] + boff[i >> 8];
        row_off[i] = r;
        cursor[i] = r;
    }
    if (i == 0) row_off[Nn] = ETot;
}

__global__ void k_scatter(const int* __restrict__ srcA, const int* __restrict__ dstA,
                          int* __restrict__ cursor, int* __restrict__ csr_src) {
    int e = blockIdx.x * blockDim.x + threadIdx.x;
    if (e >= ETot) return;
    int s, d;
    if (e < Ee) { s = srcA[e]; d = dstA[e]; } else { s = e - Ee; d = s; }
    int pos = atomicAdd(&cursor[d], 1);
    csr_src[pos] = s;
}

// ========== GEMM1 (MFMA bf16, split precision): [M,768']x[768',256] ==========
// A' = [xhi | xlo | xhi], B' = WT' = [Whi; Whi; Wlo]  (WT' stored col-major [256][768])
// Tile 128x64, BK=32, 4 waves (2x2), 16x16x32 MFMA. LDS section layout
// [kchunk][row][8 bf16] -> fragment ds_read_b128 is contiguous per 16 lanes.
__global__ __launch_bounds__(256) void k_gemm1_mfma(const ushort* __restrict__ xhi,
                                                    const ushort* __restrict__ xlo,
                                                    const ushort* __restrict__ WT,
                                                    ushort* __restrict__ h1b, int M) {
    constexpr int BM = 128, BN = 64, BK = 32, KD = 768;
    __shared__ __align__(16) ushort Al[BM * BK];   // 8 KB: kc*1024 + h*512 + i*8
    __shared__ __align__(16) ushort Bl[BN * BK];   // 4 KB: kc*512 + col*8
    const int tid = threadIdx.x;
    const int bm = blockIdx.x * BM, bn = blockIdx.y * BN;
    const int lane = tid & 63;
    const int wm = (tid >> 6) >> 1, wn = (tid >> 6) & 1;
    const int l16 = lane & 15, lk = lane >> 4;

    // staging slots: thread t -> A rows {i, 64+i} at kchunk kc; B col at kchunk kc
    const int s_kc = tid >> 6, s_i = tid & 63;
    int ar0 = bm + s_i;       ar0 = ar0 < M ? ar0 : M - 1;
    int ar1 = bm + 64 + s_i;  ar1 = ar1 < M ? ar1 : M - 1;

    f32x4 acc[4][2] = {};
    uint4 ra0, ra1, rb;
    auto load_tile = [&](int k0) {
        const ushort* asrc; int ks;
        if (k0 < 256)      { asrc = xhi; ks = k0; }
        else if (k0 < 512) { asrc = xlo; ks = k0 - 256; }
        else               { asrc = xhi; ks = k0 - 512; }
        ra0 = *(const uint4*)(asrc + (size_t)ar0 * 256 + ks + s_kc * 8);
        ra1 = *(const uint4*)(asrc + (size_t)ar1 * 256 + ks + s_kc * 8);
        rb  = *(const uint4*)(WT + (size_t)(bn + s_i) * KD + k0 + s_kc * 8);
    };
    load_tile(0);
    for (int k0 = 0; k0 < KD; k0 += BK) {
        __syncthreads();                      // prev iter's frag reads done
        *(uint4*)(Al + s_kc * 1024 + s_i * 8)       = ra0;
        *(uint4*)(Al + s_kc * 1024 + 512 + s_i * 8) = ra1;
        *(uint4*)(Bl + s_kc * 512 + s_i * 8)        = rb;
        __syncthreads();
        if (k0 + BK < KD) load_tile(k0 + BK); // prefetch next tile into regs
        bf16x8 a[4], b[2];
#pragma unroll
        for (int m = 0; m < 4; m++)
            a[m] = *(const bf16x8*)(Al + lk * 1024 + wm * 512 + (m * 16 + l16) * 8);
#pragma unroll
        for (int n = 0; n < 2; n++)
            b[n] = *(const bf16x8*)(Bl + lk * 512 + (wn * 32 + n * 16 + l16) * 8);
#pragma unroll
        for (int m = 0; m < 4; m++)
#pragma unroll
            for (int n = 0; n < 2; n++)
                acc[m][n] = __builtin_amdgcn_mfma_f32_16x16x32_bf16(a[m], b[n], acc[m][n], 0, 0, 0);
    }
    // epilogue: C row = (lane>>4)*4 + reg, col = lane&15  [verified layout]
#pragma unroll
    for (int m = 0; m < 4; m++)
#pragma unroll
        for (int n = 0; n < 2; n++)
#pragma unroll
            for (int j = 0; j < 4; j++) {
                int row = bm + wm * 64 + m * 16 + lk * 4 + j;
                if (row < M)
                    h1b[(size_t)row * 256 + bn + wn * 32 + n * 16 + l16] = f2bf(acc[m][n][j]);
            }
}

// ---------------- per-node attention coefficients (bf16 h) ----------------
template <int H, int C>
__global__ void k_alpha_b(const ushort* __restrict__ h, const float* __restrict__ a_s,
                          const float* __restrict__ a_d, float* __restrict__ asrc,
                          float* __restrict__ adst, int N) {
    __shared__ float ls[H * C], ldd[H * C];
    for (int i = threadIdx.x; i < H * C; i += blockDim.x) { ls[i] = a_s[i]; ldd[i] = a_d[i]; }
    __syncthreads();
    int t = blockIdx.x * blockDim.x + threadIdx.x;
    if (t >= N * H) return;
    int n = t / H, hh = t % H;
    const ushort* row = h + (size_t)n * (H * C) + hh * C;
    float s = 0.f, dd = 0.f;
#pragma unroll
    for (int c = 0; c < C; c += 4) {
        ushort4 v = *(const ushort4*)(row + c);
        float f0 = bf2f(v.x), f1 = bf2f(v.y), f2 = bf2f(v.z), f3 = bf2f(v.w);
        s  += f0 * ls[hh * C + c] + f1 * ls[hh * C + c + 1] +
              f2 * ls[hh * C + c + 2] + f3 * ls[hh * C + c + 3];
        dd += f0 * ldd[hh * C + c] + f1 * ldd[hh * C + c + 1] +
              f2 * ldd[hh * C + c + 2] + f3 * ldd[hh * C + c + 3];
    }
    asrc[t] = s;
    adst[t] = dd;
}

// ---------------- per-node attention coefficients (f32 h, layer 2) ----------
template <int H, int C>
__global__ void k_alpha(const float* __restrict__ h, const float* __restrict__ a_s,
                        const float* __restrict__ a_d, float* __restrict__ asrc,
                        float* __restrict__ adst, int N) {
    __shared__ float ls[H * C], ldd[H * C];
    for (int i = threadIdx.x; i < H * C; i += blockDim.x) { ls[i] = a_s[i]; ldd[i] = a_d[i]; }
    __syncthreads();
    int t = blockIdx.x * blockDim.x + threadIdx.x;
    if (t >= N * H) return;
    int n = t / H, hh = t % H;
    const float* row = h + (size_t)n * (H * C) + hh * C;
    float s = 0.f, dd = 0.f;
#pragma unroll
    for (int c = 0; c < C; c += 4) {
        float4 v = *(const float4*)(row + c);
        s  += v.x * ls[hh * C + c] + v.y * ls[hh * C + c + 1] +
              v.z * ls[hh * C + c + 2] + v.w * ls[hh * C + c + 3];
        dd += v.x * ldd[hh * C + c] + v.y * ldd[hh * C + c + 1] +
              v.z * ldd[hh * C + c + 2] + v.w * ldd[hh * C + c + 3];
    }
    asrc[t] = s;
    adst[t] = dd;
}

// ======== layer-1 aggregation: wave per node, CSR gather (bf16 h rows) =======
__global__ __launch_bounds__(256) void k_gat_aggr1(const int* __restrict__ row_off,
                                                   const int* __restrict__ csr_src,
                                                   const float* __restrict__ asrc,
                                                   const float* __restrict__ adst,
                                                   const ushort* __restrict__ h1b,
                                                   const float* __restrict__ bias,
                                                   float* __restrict__ out) {
    int wid = (blockIdx.x * 256 + threadIdx.x) >> 6;   // node id
    if (wid >= Nn) return;
    int lane = threadIdx.x & 63;
    int head = lane >> 3;
    int c0 = head * C1h + ((lane & 7) << 2);           // 4 channels within head
    int beg = row_off[wid], end = row_off[wid + 1];
    float ad = adst[(size_t)wid * H1 + head];
    float4 acc = make_float4(0.f, 0.f, 0.f, 0.f);
    float sump = 0.f;
    for (int i = beg; i < end; i++) {
        int s = csr_src[i];
        float l = asrc[(size_t)s * H1 + head] + ad;
        l = l > 0.f ? l : SLOPE * l;
        float pe = __expf(l);
        sump += pe;
        ushort4 v = *(const ushort4*)(h1b + (size_t)s * HC1 + c0);
        acc.x += pe * bf2f(v.x); acc.y += pe * bf2f(v.y);
        acc.z += pe * bf2f(v.z); acc.w += pe * bf2f(v.w);
    }
    float inv = 1.f / sump;                            // degree >= 1 (self-loop)
    float4 b4 = *(const float4*)(bias + c0);
    float4 r;
    r.x = acc.x * inv + b4.x; r.y = acc.y * inv + b4.y;
    r.z = acc.z * inv + b4.z; r.w = acc.w * inv + b4.w;
    // fused ELU
    r.x = r.x > 0.f ? r.x : __expf(r.x) - 1.f;
    r.y = r.y > 0.f ? r.y : __expf(r.y) - 1.f;
    r.z = r.z > 0.f ? r.z : __expf(r.z) - 1.f;
    r.w = r.w > 0.f ? r.w : __expf(r.w) - 1.f;
    *(float4*)(out + (size_t)wid * HC1 + c0) = r;
}

// ---------------- GEMM2: [M,256] x [256,40] -> [M,40] (fp32) ----------------
__global__ __launch_bounds__(256) void k_gemm2(const float* __restrict__ A,
                                               const float* __restrict__ B,
                                               float* __restrict__ C, int M) {
    constexpr int K = 256, NC = 40, BM = 32, BK = 32;
    __shared__ float Ws[K * NC];       // full W2: 40 KB
    __shared__ float As[BM][BK];
    const int tid = threadIdx.x;
    for (int i = tid; i < K * NC; i += 256) Ws[i] = B[i];
    const int bm = blockIdx.x * BM;
    const int r = tid >> 3, g = tid & 7;
    float acc[5] = {};
    for (int k0 = 0; k0 < K; k0 += BK) {
        int ko = (tid & 7) << 2;
        float4 v = make_float4(0.f, 0.f, 0.f, 0.f);
        if (bm + r < M) v = *(const float4*)(A + (size_t)(bm + r) * K + k0 + ko);
        *(float4*)&As[r][ko] = v;
        __syncthreads();
#pragma unroll
        for (int kk = 0; kk < BK; kk++) {
            float a = As[r][kk];
#pragma unroll
            for (int j = 0; j < 5; j++) acc[j] += a * Ws[(k0 + kk) * NC + g * 5 + j];
        }
        __syncthreads();
    }
    if (bm + r < M) {
#pragma unroll
        for (int j = 0; j < 5; j++) C[(size_t)(bm + r) * NC + g * 5 + j] = acc[j];
    }
}

// ======== layer-2 aggregation: wave per node, lanes 0..39 = channels ========
__global__ __launch_bounds__(256) void k_gat_aggr2(const int* __restrict__ row_off,
                                                   const int* __restrict__ csr_src,
                                                   const float* __restrict__ asrc,
                                                   const float* __restrict__ adst,
                                                   const float* __restrict__ h2,
                                                   const float* __restrict__ bias,
                                                   float* __restrict__ out) {
    int wid = (blockIdx.x * 256 + threadIdx.x) >> 6;
    if (wid >= Nn) return;
    int lane = threadIdx.x & 63;
    int beg = row_off[wid], end = row_off[wid + 1];
    float ad = adst[wid];
    float acc = 0.f, sump = 0.f;
    for (int i = beg; i < end; i++) {
        int s = csr_src[i];
        float l = asrc[s] + ad;
        l = l > 0.f ? l : SLOPE * l;
        float pe = __expf(l);
        sump += pe;
        if (lane < C2) acc += pe * h2[(size_t)s * C2 + lane];
    }
    if (lane < C2) out[(size_t)wid * C2 + lane] = acc / sump + bias[lane];
}

// ---------------- launch ----------------
extern "C" void kernel_launch(void* const* d_in, const int* in_sizes, int n_in,
                              void* d_out, int out_size, void* d_ws, size_t ws_size,
                              hipStream_t stream) {
    const float* x   = (const float*)d_in[0];
    const int*   ei  = (const int*)d_in[1];
    const float* w1  = (const float*)d_in[2];
    const float* as1 = (const float*)d_in[3];
    const float* ad1 = (const float*)d_in[4];
    const float* b1  = (const float*)d_in[5];
    const float* w2  = (const float*)d_in[6];
    const float* as2 = (const float*)d_in[7];
    const float* ad2 = (const float*)d_in[8];
    const float* b2  = (const float*)d_in[9];
    float* outp = (float*)d_out;

    const int* srcA = ei;          // edge_index[0]
    const int* dstA = ei + Ee;     // edge_index[1]

    char* W = (char*)d_ws;
    size_t o = 0;
    auto allocB = [&](size_t bytes) { void* p = W + o; o += (bytes + 255) & ~(size_t)255; return p; };

    ushort* xhi   = (ushort*)allocB((size_t)Nn * HC1 * 2);   // 25.6 MB
    ushort* xlo   = (ushort*)allocB((size_t)Nn * HC1 * 2);   // 25.6 MB
    float*  out1  = (float*)xhi;   // alias: out1 (51.2 MB) reuses xhi+xlo after GEMM1
    ushort* wt    = (ushort*)allocB((size_t)256 * 768 * 2);
    ushort* h1b   = (ushort*)allocB((size_t)Nn * HC1 * 2);   // 25.6 MB
    float*  h2    = (float*)allocB((size_t)Nn * C2 * 4);
    float*  asrc1 = (float*)allocB((size_t)Nn * H1 * 4);
    float*  adst1 = (float*)allocB((size_t)Nn * H1 * 4);
    float*  asrc2 = (float*)allocB((size_t)Nn * 4);
    float*  adst2 = (float*)allocB((size_t)Nn * 4);
    int* counts   = (int*)allocB((size_t)Nn * 4);
    int* exsc     = (int*)allocB((size_t)Nn * 4);
    int* bsum     = (int*)allocB(256 * 4);
    int* boff     = (int*)allocB(256 * 4);
    int* row_off  = (int*)allocB((size_t)(Nn + 1) * 4);
    int* cursor   = (int*)allocB((size_t)Nn * 4);
    int* csr_src  = (int*)allocB((size_t)ETot * 4);

    // ---- input splits (bf16 hi/lo) ----
    k_split<<<(Nn * HC1 / 4 + 255) / 256, 256, 0, stream>>>(x, xhi, xlo, Nn * HC1 / 4);
    k_wsplit<<<(256 * 256 + 255) / 256, 256, 0, stream>>>(w1, wt);

    // ---- CSR build (graph shared by both layers) ----
    hipMemsetAsync(counts, 0, (size_t)Nn * sizeof(int), stream);
    k_hist<<<(ETot + 255) / 256, 256, 0, stream>>>(dstA, counts);
    k_scan_block<<<NB_SCAN, 256, 0, stream>>>(counts, exsc, bsum);
    k_scan_top<<<1, 256, 0, stream>>>(bsum, boff);
    k_finalize_off<<<(Nn + 255) / 256, 256, 0, stream>>>(exsc, boff, row_off, cursor);
    k_scatter<<<(ETot + 255) / 256, 256, 0, stream>>>(srcA, dstA, cursor, csr_src);

    // ---- layer 1 ----
    dim3 g1((Nn + 127) / 128, 4);
    k_gemm1_mfma<<<g1, 256, 0, stream>>>(xhi, xlo, wt, h1b, Nn);
    k_alpha_b<H1, C1h><<<(Nn * H1 + 255) / 256, 256, 0, stream>>>(h1b, as1, ad1, asrc1, adst1, Nn);
    k_gat_aggr1<<<(int)(((size_t)Nn * 64 + 255) / 256), 256, 0, stream>>>(
        row_off, csr_src, asrc1, adst1, h1b, b1, out1);   // out1 overwrites xhi/xlo (dead)

    // ---- layer 2 ----
    k_gemm2<<<(Nn + 31) / 32, 256, 0, stream>>>(out1, w2, h2, Nn);
    k_alpha<1, C2><<<(Nn + 255) / 256, 256, 0, stream>>>(h2, as2, ad2, asrc2, adst2, Nn);
    k_gat_aggr2<<<(int)(((size_t)Nn * 64 + 255) / 256), 256, 0, stream>>>(
        row_off, csr_src, asrc2, adst2, h2, b2, outp);
}

// Round 4
// 386.595 us; speedup vs baseline: 9.1534x; 1.2388x over previous
//
#include <hip/hip_runtime.h>
#include <cstdint>
#include <cstddef>

// ---------------- problem constants (from setup_inputs) ----------------
constexpr int Nn   = 50000;            // nodes
constexpr int Ee   = 800000;           // edges (without self loops)
constexpr int ETot = Ee + Nn;          // 850000 with self loops
constexpr int H1   = 8;                // heads layer 1
constexpr int C1h  = 32;               // channels/head layer 1
constexpr int HC1  = 256;              // H1*C1h
constexpr int C2   = 40;               // classes (layer 2, 1 head)
constexpr float SLOPE = 0.2f;          // leaky_relu negative slope
constexpr int NB_SCAN = (Nn + 255) / 256;   // 196 scan blocks

typedef __attribute__((ext_vector_type(8))) short bf16x8;   // 8 bf16 (4 VGPRs)
typedef __attribute__((ext_vector_type(4))) float f32x4;    // MFMA accumulator

__device__ __forceinline__ ushort f2bf(float f) {           // RNE f32->bf16
    uint u = __float_as_uint(f);
    u += 0x7fffu + ((u >> 16) & 1u);
    return (ushort)(u >> 16);
}
__device__ __forceinline__ float bf2f(ushort b) {
    return __uint_as_float(((uint)b) << 16);
}

// ================= split x into bf16 hi/lo =================
__global__ void k_split(const float* __restrict__ x, ushort* __restrict__ hi,
                        ushort* __restrict__ lo, int n4) {
    int t = blockIdx.x * blockDim.x + threadIdx.x;
    if (t >= n4) return;
    float4 v = *(const float4*)(x + (size_t)t * 4);
    ushort4 h, l;
    h.x = f2bf(v.x); l.x = f2bf(v.x - bf2f(h.x));
    h.y = f2bf(v.y); l.y = f2bf(v.y - bf2f(h.y));
    h.z = f2bf(v.z); l.z = f2bf(v.z - bf2f(h.z));
    h.w = f2bf(v.w); l.w = f2bf(v.w - bf2f(h.w));
    *(ushort4*)(hi + (size_t)t * 4) = h;
    *(ushort4*)(lo + (size_t)t * 4) = l;
}

// ======= W1 [256][256] -> WT' [256 cols][768 k'] bf16: [Whi; Whi; Wlo] =======
__global__ void k_wsplit(const float* __restrict__ W, ushort* __restrict__ WT) {
    int idx = blockIdx.x * blockDim.x + threadIdx.x;   // 65536
    if (idx >= 256 * 256) return;
    int k = idx & 255, col = idx >> 8;
    float w = W[(size_t)k * 256 + col];
    ushort h = f2bf(w), l = f2bf(w - bf2f(h));
    WT[(size_t)col * 768 + k]       = h;
    WT[(size_t)col * 768 + 256 + k] = h;
    WT[(size_t)col * 768 + 512 + k] = l;
}

// ================= CSR build (histogram -> scan -> scatter) =================
__global__ void k_hist(const int* __restrict__ dstA, int* __restrict__ counts) {
    int e = blockIdx.x * blockDim.x + threadIdx.x;
    if (e >= ETot) return;
    int d = (e < Ee) ? dstA[e] : e - Ee;
    atomicAdd(&counts[d], 1);
}

__global__ __launch_bounds__(256) void k_scan_block(const int* __restrict__ counts,
                                                    int* __restrict__ exsc,
                                                    int* __restrict__ bsum) {
    __shared__ int sm[256];
    int i = blockIdx.x * 256 + threadIdx.x;
    int v = (i < Nn) ? counts[i] : 0;
    sm[threadIdx.x] = v;
    __syncthreads();
#pragma unroll
    for (int off = 1; off < 256; off <<= 1) {
        int t = (threadIdx.x >= off) ? sm[threadIdx.x - off] : 0;
        __syncthreads();
        sm[threadIdx.x] += t;
        __syncthreads();
    }
    if (i < Nn) exsc[i] = sm[threadIdx.x] - v;
    if (threadIdx.x == 255) bsum[blockIdx.x] = sm[255];
}

__global__ __launch_bounds__(256) void k_scan_top(const int* __restrict__ bsum,
                                                  int* __restrict__ boff) {
    __shared__ int sm[256];
    int t = threadIdx.x;
    int v = (t < NB_SCAN) ? bsum[t] : 0;
    sm[t] = v;
    __syncthreads();
#pragma unroll
    for (int off = 1; off < 256; off <<= 1) {
        int x = (t >= off) ? sm[t - off] : 0;
        __syncthreads();
        sm[t] += x;
        __syncthreads();
    }
    if (t < NB_SCAN) boff[t] = sm[t] - v;
}

__global__ void k_finalize_off(const int* __restrict__ exsc, const int* __restrict__ boff,
                               int* __restrict__ row_off, int* __restrict__ cursor) {
    int i = blockIdx.x * blockDim.x + threadIdx.x;
    if (i < Nn) {
        int r = exsc[i] + boff[i >> 8];
        row_off[i] = r;
        cursor[i] = r;
    }
    if (i == 0) row_off[Nn] = ETot;
}

__global__ void k_scatter(const int* __restrict__ srcA, const int* __restrict__ dstA,
                          int* __restrict__ cursor, int* __restrict__ csr_src) {
    int e = blockIdx.x * blockDim.x + threadIdx.x;
    if (e >= ETot) return;
    int s, d;
    if (e < Ee) { s = srcA[e]; d = dstA[e]; } else { s = e - Ee; d = s; }
    int pos = atomicAdd(&cursor[d], 1);
    csr_src[pos] = s;
}

// ========== GEMM1 (MFMA bf16, split precision): [M,768']x[768',256] ==========
__global__ __launch_bounds__(256) void k_gemm1_mfma(const ushort* __restrict__ xhi,
                                                    const ushort* __restrict__ xlo,
                                                    const ushort* __restrict__ WT,
                                                    ushort* __restrict__ h1b, int M) {
    constexpr int BM = 128, BN = 64, BK = 32, KD = 768;
    __shared__ __align__(16) ushort Al[BM * BK];   // 8 KB: kc*1024 + h*512 + i*8
    __shared__ __align__(16) ushort Bl[BN * BK];   // 4 KB: kc*512 + col*8
    const int tid = threadIdx.x;
    const int bm = blockIdx.x * BM, bn = blockIdx.y * BN;
    const int lane = tid & 63;
    const int wm = (tid >> 6) >> 1, wn = (tid >> 6) & 1;
    const int l16 = lane & 15, lk = lane >> 4;

    const int s_kc = tid >> 6, s_i = tid & 63;
    int ar0 = bm + s_i;       ar0 = ar0 < M ? ar0 : M - 1;
    int ar1 = bm + 64 + s_i;  ar1 = ar1 < M ? ar1 : M - 1;

    f32x4 acc[4][2] = {};
    uint4 ra0, ra1, rb;
    auto load_tile = [&](int k0) {
        const ushort* asrc; int ks;
        if (k0 < 256)      { asrc = xhi; ks = k0; }
        else if (k0 < 512) { asrc = xlo; ks = k0 - 256; }
        else               { asrc = xhi; ks = k0 - 512; }
        ra0 = *(const uint4*)(asrc + (size_t)ar0 * 256 + ks + s_kc * 8);
        ra1 = *(const uint4*)(asrc + (size_t)ar1 * 256 + ks + s_kc * 8);
        rb  = *(const uint4*)(WT + (size_t)(bn + s_i) * KD + k0 + s_kc * 8);
    };
    load_tile(0);
    for (int k0 = 0; k0 < KD; k0 += BK) {
        __syncthreads();
        *(uint4*)(Al + s_kc * 1024 + s_i * 8)       = ra0;
        *(uint4*)(Al + s_kc * 1024 + 512 + s_i * 8) = ra1;
        *(uint4*)(Bl + s_kc * 512 + s_i * 8)        = rb;
        __syncthreads();
        if (k0 + BK < KD) load_tile(k0 + BK);
        bf16x8 a[4], b[2];
#pragma unroll
        for (int m = 0; m < 4; m++)
            a[m] = *(const bf16x8*)(Al + lk * 1024 + wm * 512 + (m * 16 + l16) * 8);
#pragma unroll
        for (int n = 0; n < 2; n++)
            b[n] = *(const bf16x8*)(Bl + lk * 512 + (wn * 32 + n * 16 + l16) * 8);
#pragma unroll
        for (int m = 0; m < 4; m++)
#pragma unroll
            for (int n = 0; n < 2; n++)
                acc[m][n] = __builtin_amdgcn_mfma_f32_16x16x32_bf16(a[m], b[n], acc[m][n], 0, 0, 0);
    }
#pragma unroll
    for (int m = 0; m < 4; m++)
#pragma unroll
        for (int n = 0; n < 2; n++)
#pragma unroll
            for (int j = 0; j < 4; j++) {
                int row = bm + wm * 64 + m * 16 + lk * 4 + j;
                if (row < M)
                    h1b[(size_t)row * 256 + bn + wn * 32 + n * 16 + l16] = f2bf(acc[m][n][j]);
            }
}

// ---------------- per-node attention coefficients (bf16 h) ----------------
template <int H, int C>
__global__ void k_alpha_b(const ushort* __restrict__ h, const float* __restrict__ a_s,
                          const float* __restrict__ a_d, float* __restrict__ asrc,
                          float* __restrict__ adst, int N) {
    __shared__ float ls[H * C], ldd[H * C];
    for (int i = threadIdx.x; i < H * C; i += blockDim.x) { ls[i] = a_s[i]; ldd[i] = a_d[i]; }
    __syncthreads();
    int t = blockIdx.x * blockDim.x + threadIdx.x;
    if (t >= N * H) return;
    int n = t / H, hh = t % H;
    const ushort* row = h + (size_t)n * (H * C) + hh * C;
    float s = 0.f, dd = 0.f;
#pragma unroll
    for (int c = 0; c < C; c += 4) {
        ushort4 v = *(const ushort4*)(row + c);
        float f0 = bf2f(v.x), f1 = bf2f(v.y), f2 = bf2f(v.z), f3 = bf2f(v.w);
        s  += f0 * ls[hh * C + c] + f1 * ls[hh * C + c + 1] +
              f2 * ls[hh * C + c + 2] + f3 * ls[hh * C + c + 3];
        dd += f0 * ldd[hh * C + c] + f1 * ldd[hh * C + c + 1] +
              f2 * ldd[hh * C + c + 2] + f3 * ldd[hh * C + c + 3];
    }
    asrc[t] = s;
    adst[t] = dd;
}

// ---------------- per-node attention coefficients (f32 h, layer 2) ----------
template <int H, int C>
__global__ void k_alpha(const float* __restrict__ h, const float* __restrict__ a_s,
                        const float* __restrict__ a_d, float* __restrict__ asrc,
                        float* __restrict__ adst, int N) {
    __shared__ float ls[H * C], ldd[H * C];
    for (int i = threadIdx.x; i < H * C; i += blockDim.x) { ls[i] = a_s[i]; ldd[i] = a_d[i]; }
    __syncthreads();
    int t = blockIdx.x * blockDim.x + threadIdx.x;
    if (t >= N * H) return;
    int n = t / H, hh = t % H;
    const float* row = h + (size_t)n * (H * C) + hh * C;
    float s = 0.f, dd = 0.f;
#pragma unroll
    for (int c = 0; c < C; c += 4) {
        float4 v = *(const float4*)(row + c);
        s  += v.x * ls[hh * C + c] + v.y * ls[hh * C + c + 1] +
              v.z * ls[hh * C + c + 2] + v.w * ls[hh * C + c + 3];
        dd += v.x * ldd[hh * C + c] + v.y * ldd[hh * C + c + 1] +
              v.z * ldd[hh * C + c + 2] + v.w * ldd[hh * C + c + 3];
    }
    asrc[t] = s;
    adst[t] = dd;
}

// ======== layer-1 aggregation: wave/node, CSR gather, 4-wide unrolled ========
__global__ __launch_bounds__(256) void k_gat_aggr1(const int* __restrict__ row_off,
                                                   const int* __restrict__ csr_src,
                                                   const float* __restrict__ asrc,
                                                   const float* __restrict__ adst,
                                                   const ushort* __restrict__ h1b,
                                                   const float* __restrict__ bias,
                                                   float* __restrict__ out) {
    int wid = (blockIdx.x * 256 + threadIdx.x) >> 6;   // node id
    if (wid >= Nn) return;
    int lane = threadIdx.x & 63;
    int head = lane >> 3;
    int c0 = head * C1h + ((lane & 7) << 2);
    int beg = row_off[wid], end = row_off[wid + 1];
    float ad = adst[(size_t)wid * H1 + head];
    float4 acc = make_float4(0.f, 0.f, 0.f, 0.f);
    float sump = 0.f;
    int i = beg;
    for (; i + 3 < end; i += 4) {
        int s0 = csr_src[i], s1 = csr_src[i + 1], s2 = csr_src[i + 2], s3 = csr_src[i + 3];
        float a0 = asrc[(size_t)s0 * H1 + head], a1 = asrc[(size_t)s1 * H1 + head];
        float a2 = asrc[(size_t)s2 * H1 + head], a3 = asrc[(size_t)s3 * H1 + head];
        ushort4 v0 = *(const ushort4*)(h1b + (size_t)s0 * HC1 + c0);
        ushort4 v1 = *(const ushort4*)(h1b + (size_t)s1 * HC1 + c0);
        ushort4 v2 = *(const ushort4*)(h1b + (size_t)s2 * HC1 + c0);
        ushort4 v3 = *(const ushort4*)(h1b + (size_t)s3 * HC1 + c0);
        float l0 = a0 + ad; l0 = l0 > 0.f ? l0 : SLOPE * l0;
        float l1 = a1 + ad; l1 = l1 > 0.f ? l1 : SLOPE * l1;
        float l2 = a2 + ad; l2 = l2 > 0.f ? l2 : SLOPE * l2;
        float l3 = a3 + ad; l3 = l3 > 0.f ? l3 : SLOPE * l3;
        float p0 = __expf(l0), p1 = __expf(l1), p2 = __expf(l2), p3 = __expf(l3);
        sump += (p0 + p1) + (p2 + p3);
        acc.x += p0 * bf2f(v0.x) + p1 * bf2f(v1.x) + p2 * bf2f(v2.x) + p3 * bf2f(v3.x);
        acc.y += p0 * bf2f(v0.y) + p1 * bf2f(v1.y) + p2 * bf2f(v2.y) + p3 * bf2f(v3.y);
        acc.z += p0 * bf2f(v0.z) + p1 * bf2f(v1.z) + p2 * bf2f(v2.z) + p3 * bf2f(v3.z);
        acc.w += p0 * bf2f(v0.w) + p1 * bf2f(v1.w) + p2 * bf2f(v2.w) + p3 * bf2f(v3.w);
    }
    for (; i < end; i++) {
        int s = csr_src[i];
        float l = asrc[(size_t)s * H1 + head] + ad;
        l = l > 0.f ? l : SLOPE * l;
        float pe = __expf(l);
        sump += pe;
        ushort4 v = *(const ushort4*)(h1b + (size_t)s * HC1 + c0);
        acc.x += pe * bf2f(v.x); acc.y += pe * bf2f(v.y);
        acc.z += pe * bf2f(v.z); acc.w += pe * bf2f(v.w);
    }
    float inv = 1.f / sump;
    float4 b4 = *(const float4*)(bias + c0);
    float4 r;
    r.x = acc.x * inv + b4.x; r.y = acc.y * inv + b4.y;
    r.z = acc.z * inv + b4.z; r.w = acc.w * inv + b4.w;
    r.x = r.x > 0.f ? r.x : __expf(r.x) - 1.f;
    r.y = r.y > 0.f ? r.y : __expf(r.y) - 1.f;
    r.z = r.z > 0.f ? r.z : __expf(r.z) - 1.f;
    r.w = r.w > 0.f ? r.w : __expf(r.w) - 1.f;
    *(float4*)(out + (size_t)wid * HC1 + c0) = r;
}

// ---------------- GEMM2: [M,256] x [256,40] -> [M,40] (fp32) ----------------
__global__ __launch_bounds__(256) void k_gemm2(const float* __restrict__ A,
                                               const float* __restrict__ B,
                                               float* __restrict__ C, int M) {
    constexpr int K = 256, NC = 40, BM = 32, BK = 32;
    __shared__ float Ws[K * NC];
    __shared__ float As[BM][BK];
    const int tid = threadIdx.x;
    for (int i = tid; i < K * NC; i += 256) Ws[i] = B[i];
    const int bm = blockIdx.x * BM;
    const int r = tid >> 3, g = tid & 7;
    float acc[5] = {};
    for (int k0 = 0; k0 < K; k0 += BK) {
        int ko = (tid & 7) << 2;
        float4 v = make_float4(0.f, 0.f, 0.f, 0.f);
        if (bm + r < M) v = *(const float4*)(A + (size_t)(bm + r) * K + k0 + ko);
        *(float4*)&As[r][ko] = v;
        __syncthreads();
#pragma unroll
        for (int kk = 0; kk < BK; kk++) {
            float a = As[r][kk];
#pragma unroll
            for (int j = 0; j < 5; j++) acc[j] += a * Ws[(k0 + kk) * NC + g * 5 + j];
        }
        __syncthreads();
    }
    if (bm + r < M) {
#pragma unroll
        for (int j = 0; j < 5; j++) C[(size_t)(bm + r) * NC + g * 5 + j] = acc[j];
    }
}

// ======== layer-2 aggregation: wave/node, lanes 0..39, 4-wide unrolled ======
__global__ __launch_bounds__(256) void k_gat_aggr2(const int* __restrict__ row_off,
                                                   const int* __restrict__ csr_src,
                                                   const float* __restrict__ asrc,
                                                   const float* __restrict__ adst,
                                                   const float* __restrict__ h2,
                                                   const float* __restrict__ bias,
                                                   float* __restrict__ out) {
    int wid = (blockIdx.x * 256 + threadIdx.x) >> 6;
    if (wid >= Nn) return;
    int lane = threadIdx.x & 63;
    int cl = lane < C2 ? lane : C2 - 1;            // clamp: lanes 40..63 read c39
    int beg = row_off[wid], end = row_off[wid + 1];
    float ad = adst[wid];
    float acc = 0.f, sump = 0.f;
    int i = beg;
    for (; i + 3 < end; i += 4) {
        int s0 = csr_src[i], s1 = csr_src[i + 1], s2 = csr_src[i + 2], s3 = csr_src[i + 3];
        float a0 = asrc[s0], a1 = asrc[s1], a2 = asrc[s2], a3 = asrc[s3];
        float v0 = h2[(size_t)s0 * C2 + cl];
        float v1 = h2[(size_t)s1 * C2 + cl];
        float v2 = h2[(size_t)s2 * C2 + cl];
        float v3 = h2[(size_t)s3 * C2 + cl];
        float l0 = a0 + ad; l0 = l0 > 0.f ? l0 : SLOPE * l0;
        float l1 = a1 + ad; l1 = l1 > 0.f ? l1 : SLOPE * l1;
        float l2 = a2 + ad; l2 = l2 > 0.f ? l2 : SLOPE * l2;
        float l3 = a3 + ad; l3 = l3 > 0.f ? l3 : SLOPE * l3;
        float p0 = __expf(l0), p1 = __expf(l1), p2 = __expf(l2), p3 = __expf(l3);
        sump += (p0 + p1) + (p2 + p3);
        acc += p0 * v0 + p1 * v1 + p2 * v2 + p3 * v3;
    }
    for (; i < end; i++) {
        int s = csr_src[i];
        float l = asrc[s] + ad;
        l = l > 0.f ? l : SLOPE * l;
        float pe = __expf(l);
        sump += pe;
        acc += pe * h2[(size_t)s * C2 + cl];
    }
    if (lane < C2) out[(size_t)wid * C2 + lane] = acc / sump + bias[lane];
}

// ---------------- launch ----------------
extern "C" void kernel_launch(void* const* d_in, const int* in_sizes, int n_in,
                              void* d_out, int out_size, void* d_ws, size_t ws_size,
                              hipStream_t stream) {
    const float* x   = (const float*)d_in[0];
    const int*   ei  = (const int*)d_in[1];
    const float* w1  = (const float*)d_in[2];
    const float* as1 = (const float*)d_in[3];
    const float* ad1 = (const float*)d_in[4];
    const float* b1  = (const float*)d_in[5];
    const float* w2  = (const float*)d_in[6];
    const float* as2 = (const float*)d_in[7];
    const float* ad2 = (const float*)d_in[8];
    const float* b2  = (const float*)d_in[9];
    float* outp = (float*)d_out;

    const int* srcA = ei;
    const int* dstA = ei + Ee;

    char* W = (char*)d_ws;
    size_t o = 0;
    auto allocB = [&](size_t bytes) { void* p = W + o; o += (bytes + 255) & ~(size_t)255; return p; };

    ushort* xhi   = (ushort*)allocB((size_t)Nn * HC1 * 2);   // 25.6 MB
    ushort* xlo   = (ushort*)allocB((size_t)Nn * HC1 * 2);   // 25.6 MB
    float*  out1  = (float*)xhi;   // alias: reuses xhi+xlo after GEMM1
    ushort* wt    = (ushort*)allocB((size_t)256 * 768 * 2);
    ushort* h1b   = (ushort*)allocB((size_t)Nn * HC1 * 2);   // 25.6 MB
    float*  h2    = (float*)allocB((size_t)Nn * C2 * 4);
    float*  asrc1 = (float*)allocB((size_t)Nn * H1 * 4);
    float*  adst1 = (float*)allocB((size_t)Nn * H1 * 4);
    float*  asrc2 = (float*)allocB((size_t)Nn * 4);
    float*  adst2 = (float*)allocB((size_t)Nn * 4);
    int* counts   = (int*)allocB((size_t)Nn * 4);
    int* exsc     = (int*)allocB((size_t)Nn * 4);
    int* bsum     = (int*)allocB(256 * 4);
    int* boff     = (int*)allocB(256 * 4);
    int* row_off  = (int*)allocB((size_t)(Nn + 1) * 4);
    int* cursor   = (int*)allocB((size_t)Nn * 4);
    int* csr_src  = (int*)allocB((size_t)ETot * 4);

    // ---- input splits (bf16 hi/lo) ----
    k_split<<<(Nn * HC1 / 4 + 255) / 256, 256, 0, stream>>>(x, xhi, xlo, Nn * HC1 / 4);
    k_wsplit<<<(256 * 256 + 255) / 256, 256, 0, stream>>>(w1, wt);

    // ---- CSR build (graph shared by both layers) ----
    hipMemsetAsync(counts, 0, (size_t)Nn * sizeof(int), stream);
    k_hist<<<(ETot + 255) / 256, 256, 0, stream>>>(dstA, counts);
    k_scan_block<<<NB_SCAN, 256, 0, stream>>>(counts, exsc, bsum);
    k_scan_top<<<1, 256, 0, stream>>>(bsum, boff);
    k_finalize_off<<<(Nn + 255) / 256, 256, 0, stream>>>(exsc, boff, row_off, cursor);
    k_scatter<<<(ETot + 255) / 256, 256, 0, stream>>>(srcA, dstA, cursor, csr_src);

    // ---- layer 1 ----
    dim3 g1((Nn + 127) / 128, 4);
    k_gemm1_mfma<<<g1, 256, 0, stream>>>(xhi, xlo, wt, h1b, Nn);
    k_alpha_b<H1, C1h><<<(Nn * H1 + 255) / 256, 256, 0, stream>>>(h1b, as1, ad1, asrc1, adst1, Nn);
    k_gat_aggr1<<<(int)(((size_t)Nn * 64 + 255) / 256), 256, 0, stream>>>(
        row_off, csr_src, asrc1, adst1, h1b, b1, out1);

    // ---- layer 2 ----
    k_gemm2<<<(Nn + 31) / 32, 256, 0, stream>>>(out1, w2, h2, Nn);
    k_alpha<1, C2><<<(Nn + 255) / 256, 256, 0, stream>>>(h2, as2, ad2, asrc2, adst2, Nn);
    k_gat_aggr2<<<(int)(((size_t)Nn * 64 + 255) / 256), 256, 0, stream>>>(
        row_off, csr_src, asrc2, adst2, h2, b2, outp);
}